// Round 2
// baseline (9022.153 us; speedup 1.0000x reference)
//
#include <hip/hip_runtime.h>
#include <math.h>

#define BM 128
#define BN 128
#define BK 16
#define LPAD 4

static constexpr int Bb = 4, Nn = 4096, Dd = 1024, Ee = 8, Ss = 512, Hh = 4096;
static constexpr int ES = Ee * Ss;        // 4096

// ---------------- RMSNorm: one block per row, d=1024 = 256 threads * float4
__global__ __launch_bounds__(256)
void rmsnorm_kernel(const float* __restrict__ in, const float* __restrict__ gamma,
                    float* __restrict__ out)
{
    const int row = blockIdx.x;
    const int t = threadIdx.x;
    const float4 v = reinterpret_cast<const float4*>(in + (size_t)row * Dd)[t];
    float ss = v.x * v.x + v.y * v.y + v.z * v.z + v.w * v.w;
#pragma unroll
    for (int off = 32; off > 0; off >>= 1) ss += __shfl_down(ss, off);
    __shared__ float sm[4];
    if ((t & 63) == 0) sm[t >> 6] = ss;
    __syncthreads();
    const float tot = sm[0] + sm[1] + sm[2] + sm[3];
    const float scale = 32.0f / fmaxf(sqrtf(tot), 1e-12f);   // sqrt(1024)=32
    const float4 g = reinterpret_cast<const float4*>(gamma)[t];
    float4 o;
    o.x = v.x * scale * g.x; o.y = v.y * scale * g.y;
    o.z = v.z * scale * g.z; o.w = v.w * scale * g.w;
    reinterpret_cast<float4*>(out + (size_t)row * Dd)[t] = o;
}

// ---------------- dispatch softmax stats (over n), single batch b
// logits_b is [Nn, ES]; partial over chunks of 512 rows
__global__ __launch_bounds__(256)
void colstats_partial(const float* __restrict__ logits, float2* __restrict__ pstats)
{
    const int col = blockIdx.x * 256 + threadIdx.x;  // es
    const int ch = blockIdx.y;                       // chunk of 512 rows
    const float* p = logits + (size_t)ch * 512 * ES + col;
    float m = -3.0e38f, s = 0.0f;
#pragma unroll 4
    for (int r = 0; r < 512; ++r) {
        const float v = *p; p += ES;
        const float nm = fmaxf(m, v);
        s = s * __expf(m - nm) + __expf(v - nm);
        m = nm;
    }
    pstats[(size_t)ch * ES + col] = make_float2(m, s);
}

__global__ __launch_bounds__(256)
void colstats_combine(const float2* __restrict__ pstats, float2* __restrict__ dstats)
{
    const int col = blockIdx.x * 256 + threadIdx.x;  // 0..4095
    float M = -3.0e38f, S = 0.0f;
#pragma unroll
    for (int c = 0; c < 8; ++c) {
        const float2 pr = pstats[(size_t)c * ES + col];
        const float nm = fmaxf(M, pr.x);
        S = S * __expf(M - nm) + pr.y * __expf(pr.x - nm);
        M = nm;
    }
    dstats[col] = make_float2(M, 1.0f / S);
}

// ---------------- combine softmax stats (over e*s): one block per n row
__global__ __launch_bounds__(256)
void rowstats_kernel(const float* __restrict__ logits, float2* __restrict__ cstats)
{
    const int row = blockIdx.x;
    const int t = threadIdx.x;
    const float* p = logits + (size_t)row * ES;
    float m = -3.0e38f, s = 0.0f;
#pragma unroll 4
    for (int i = t; i < ES; i += 256) {
        const float v = p[i];
        const float nm = fmaxf(m, v);
        s = s * __expf(m - nm) + __expf(v - nm);
        m = nm;
    }
#pragma unroll
    for (int off = 32; off > 0; off >>= 1) {
        const float om = __shfl_down(m, off);
        const float os = __shfl_down(s, off);
        const float nm = fmaxf(m, om);
        s = s * __expf(m - nm) + os * __expf(om - nm);
        m = nm;
    }
    __shared__ float2 sm[4];
    if ((t & 63) == 0) sm[t >> 6] = make_float2(m, s);
    __syncthreads();
    if (t == 0) {
        float M = sm[0].x, S = sm[0].y;
#pragma unroll
        for (int w = 1; w < 4; ++w) {
            const float nm = fmaxf(M, sm[w].x);
            S = S * __expf(M - nm) + sm[w].y * __expf(sm[w].x - nm);
            M = nm;
        }
        cstats[row] = make_float2(M, 1.0f / S);
    }
}

// ---------------- templated fp32 SGEMM, 128x128x16 tile, 256 thr, 8x8/thread
// AMODE: 0 = A[M,K]; 1 = A[K,M]; 2 = A[K,M] * dispatch-softmax weights (stats by m)
//        3 = A[M,K] * combine-softmax weights (stats by m)
// BTRANS: 0 = B[K,N]; 1 = B[N,K]
// EPI: 0 none; 1 gelu(c+bias[n]); 2 c+bias[n]
// z-batched via blockIdx.z with element strides sAz/sBz/sCz/sBiasZ.
template<int AMODE, int BTRANS, int EPI>
__global__ __launch_bounds__(256, 2)
void sgemm_kernel(const float* __restrict__ A, const float* __restrict__ B,
                  float* __restrict__ C, int K, int lda, int ldb, int ldc,
                  const float2* __restrict__ stats, const float* __restrict__ bias,
                  long long sAz, long long sBz, long long sCz, long long sBiasZ)
{
    __shared__ float As[BK][BM + LPAD];
    __shared__ float Bs[BK][BN + LPAD];

    const int tid = threadIdx.x;
    const int tx = tid & 15;
    const int ty = tid >> 4;
    const int bm = blockIdx.y * BM;
    const int bn = blockIdx.x * BN;
    A += (size_t)blockIdx.z * sAz;
    B += (size_t)blockIdx.z * sBz;
    C += (size_t)blockIdx.z * sCz;
    if (bias) bias += (size_t)blockIdx.z * sBiasZ;

    float acc[8][8];
#pragma unroll
    for (int i = 0; i < 8; ++i)
#pragma unroll
        for (int j = 0; j < 8; ++j) acc[i][j] = 0.0f;

    const int ar  = tid >> 2;   // 0..63  (row for [M,K]-style tiles)
    const int akq = tid & 3;    // float4 index along K
    const int ak  = tid >> 5;   // 0..7   (k for [K,M]-style tiles)
    const int amq = tid & 31;   // float4 index along M/N

    const float *Ap0, *Ap1, *Bp0, *Bp1;
    size_t stepA, stepB;
    if constexpr (AMODE == 0 || AMODE == 3) {
        Ap0 = A + (size_t)(bm + ar) * lda + akq * 4;
        Ap1 = A + (size_t)(bm + ar + 64) * lda + akq * 4;
        stepA = BK;
    } else {
        Ap0 = A + (size_t)ak * lda + bm + amq * 4;
        Ap1 = A + (size_t)(ak + 8) * lda + bm + amq * 4;
        stepA = (size_t)BK * lda;
    }
    if constexpr (BTRANS == 0) {
        Bp0 = B + (size_t)ak * ldb + bn + amq * 4;
        Bp1 = B + (size_t)(ak + 8) * ldb + bn + amq * 4;
        stepB = (size_t)BK * ldb;
    } else {
        Bp0 = B + (size_t)(bn + ar) * ldb + akq * 4;
        Bp1 = B + (size_t)(bn + ar + 64) * ldb + akq * 4;
        stepB = BK;
    }

    float2 stA[4], st0, st1;
    if constexpr (AMODE == 2) {
#pragma unroll
        for (int u = 0; u < 4; ++u) stA[u] = stats[bm + amq * 4 + u];
    }
    if constexpr (AMODE == 3) {
        st0 = stats[bm + ar];
        st1 = stats[bm + ar + 64];
    }

    float4 ra0, ra1, rb0, rb1;
    ra0 = *(const float4*)Ap0; ra1 = *(const float4*)Ap1;
    rb0 = *(const float4*)Bp0; rb1 = *(const float4*)Bp1;
    Ap0 += stepA; Ap1 += stepA; Bp0 += stepB; Bp1 += stepB;

    const int nkt = K / BK;
    for (int kt = 0; kt < nkt; ++kt) {
        __syncthreads();
        // ---- store A tile
        if constexpr (AMODE == 0) {
            As[akq * 4 + 0][ar] = ra0.x; As[akq * 4 + 1][ar] = ra0.y;
            As[akq * 4 + 2][ar] = ra0.z; As[akq * 4 + 3][ar] = ra0.w;
            As[akq * 4 + 0][ar + 64] = ra1.x; As[akq * 4 + 1][ar + 64] = ra1.y;
            As[akq * 4 + 2][ar + 64] = ra1.z; As[akq * 4 + 3][ar + 64] = ra1.w;
        } else if constexpr (AMODE == 3) {
            As[akq * 4 + 0][ar] = __expf(ra0.x - st0.x) * st0.y;
            As[akq * 4 + 1][ar] = __expf(ra0.y - st0.x) * st0.y;
            As[akq * 4 + 2][ar] = __expf(ra0.z - st0.x) * st0.y;
            As[akq * 4 + 3][ar] = __expf(ra0.w - st0.x) * st0.y;
            As[akq * 4 + 0][ar + 64] = __expf(ra1.x - st1.x) * st1.y;
            As[akq * 4 + 1][ar + 64] = __expf(ra1.y - st1.x) * st1.y;
            As[akq * 4 + 2][ar + 64] = __expf(ra1.z - st1.x) * st1.y;
            As[akq * 4 + 3][ar + 64] = __expf(ra1.w - st1.x) * st1.y;
        } else if constexpr (AMODE == 1) {
            *(float4*)&As[ak][amq * 4] = ra0;
            *(float4*)&As[ak + 8][amq * 4] = ra1;
        } else { // AMODE == 2
            float4 w0, w1v;
            w0.x = __expf(ra0.x - stA[0].x) * stA[0].y;
            w0.y = __expf(ra0.y - stA[1].x) * stA[1].y;
            w0.z = __expf(ra0.z - stA[2].x) * stA[2].y;
            w0.w = __expf(ra0.w - stA[3].x) * stA[3].y;
            w1v.x = __expf(ra1.x - stA[0].x) * stA[0].y;
            w1v.y = __expf(ra1.y - stA[1].x) * stA[1].y;
            w1v.z = __expf(ra1.z - stA[2].x) * stA[2].y;
            w1v.w = __expf(ra1.w - stA[3].x) * stA[3].y;
            *(float4*)&As[ak][amq * 4] = w0;
            *(float4*)&As[ak + 8][amq * 4] = w1v;
        }
        // ---- store B tile
        if constexpr (BTRANS == 0) {
            *(float4*)&Bs[ak][amq * 4] = rb0;
            *(float4*)&Bs[ak + 8][amq * 4] = rb1;
        } else {
            Bs[akq * 4 + 0][ar] = rb0.x; Bs[akq * 4 + 1][ar] = rb0.y;
            Bs[akq * 4 + 2][ar] = rb0.z; Bs[akq * 4 + 3][ar] = rb0.w;
            Bs[akq * 4 + 0][ar + 64] = rb1.x; Bs[akq * 4 + 1][ar + 64] = rb1.y;
            Bs[akq * 4 + 2][ar + 64] = rb1.z; Bs[akq * 4 + 3][ar + 64] = rb1.w;
        }
        __syncthreads();
        if (kt + 1 < nkt) {   // register prefetch of next tile
            ra0 = *(const float4*)Ap0; ra1 = *(const float4*)Ap1;
            rb0 = *(const float4*)Bp0; rb1 = *(const float4*)Bp1;
            Ap0 += stepA; Ap1 += stepA; Bp0 += stepB; Bp1 += stepB;
        }
#pragma unroll
        for (int k = 0; k < BK; ++k) {
            const float4 a0 = *(const float4*)&As[k][ty * 4];
            const float4 a1 = *(const float4*)&As[k][ty * 4 + 64];
            const float4 b0 = *(const float4*)&Bs[k][tx * 4];
            const float4 b1 = *(const float4*)&Bs[k][tx * 4 + 64];
            const float av[8] = {a0.x, a0.y, a0.z, a0.w, a1.x, a1.y, a1.z, a1.w};
            const float bv[8] = {b0.x, b0.y, b0.z, b0.w, b1.x, b1.y, b1.z, b1.w};
#pragma unroll
            for (int i = 0; i < 8; ++i)
#pragma unroll
                for (int j = 0; j < 8; ++j)
                    acc[i][j] = fmaf(av[i], bv[j], acc[i][j]);
        }
    }

    // ---- epilogue
    float bv0[4] = {0.f, 0.f, 0.f, 0.f}, bv1[4] = {0.f, 0.f, 0.f, 0.f};
    if constexpr (EPI != 0) {
        const float4 t0 = *(const float4*)&bias[bn + tx * 4];
        const float4 t1 = *(const float4*)&bias[bn + tx * 4 + 64];
        bv0[0] = t0.x; bv0[1] = t0.y; bv0[2] = t0.z; bv0[3] = t0.w;
        bv1[0] = t1.x; bv1[1] = t1.y; bv1[2] = t1.z; bv1[3] = t1.w;
    }
    auto ep = [&](float v, float bb) -> float {
        if constexpr (EPI == 1) {
            const float u = v + bb;
            return 0.5f * u * (1.0f + erff(u * 0.70710678118654752f));
        } else if constexpr (EPI == 2) {
            return v + bb;
        } else {
            return v;
        }
    };
#pragma unroll
    for (int i = 0; i < 8; ++i) {
        const int m = bm + ty * 4 + (i < 4 ? i : 60 + i);
        float* cp = C + (size_t)m * ldc + bn;
        float4 o0, o1;
        o0.x = ep(acc[i][0], bv0[0]); o0.y = ep(acc[i][1], bv0[1]);
        o0.z = ep(acc[i][2], bv0[2]); o0.w = ep(acc[i][3], bv0[3]);
        o1.x = ep(acc[i][4], bv1[0]); o1.y = ep(acc[i][5], bv1[1]);
        o1.z = ep(acc[i][6], bv1[2]); o1.w = ep(acc[i][7], bv1[3]);
        *(float4*)(cp + tx * 4) = o0;
        *(float4*)(cp + tx * 4 + 64) = o1;
    }
}

extern "C" void kernel_launch(void* const* d_in, const int* in_sizes, int n_in,
                              void* d_out, int out_size, void* d_ws, size_t ws_size,
                              hipStream_t stream)
{
    const float* x           = (const float*)d_in[0];
    const float* gamma       = (const float*)d_in[1];
    const float* slot_gamma  = (const float*)d_in[2];
    const float* slot_embeds = (const float*)d_in[3];
    const float* w1          = (const float*)d_in[4];
    const float* b1          = (const float*)d_in[5];
    const float* w2          = (const float*)d_in[6];
    const float* b2          = (const float*)d_in[7];
    float* out = (float*)d_out;

    // ---- workspace layout (floats), per-batch processing. Total 50,413,568
    // floats = 201.7 MB. HARD GUARD: if ws is smaller, do nothing (loud fail,
    // no OOB corruption — round-1 failure was OOB stomping pristine inputs).
    const size_t NEED_FLOATS = 50413568ull;
    if (ws_size < NEED_FLOATS * 4) return;

    float* ws = (float*)d_ws;
    float* se      = ws;                        //  4,194,304 [es,d] normed slot embeds
    float* xn      = se + 4194304ull;           //  4,194,304 [n,d] normed x, batch b
    float* logits  = xn + 4194304ull;           // 16,777,216 [n,es] logits, batch b
    float* slots   = logits + 16777216ull;      //  4,194,304 [es,d]
    float* outb    = slots + 4194304ull;        //  4,194,304 [es,d]
    float* hid     = outb + 4194304ull;         // 16,777,216 [es,h] (z=expert rows)
    float2* dstats = (float2*)(hid + 16777216ull); // 4096 float2
    float2* cstats = dstats + 4096;                // 4096 float2
    float2* pstats = cstats + 4096;                // 32768 float2

    // 0) slot-embed RMSNorm (once)
    rmsnorm_kernel<<<ES, 256, 0, stream>>>(slot_embeds, slot_gamma, se);

    for (int b = 0; b < Bb; ++b) {
        const float* xb = x + (size_t)b * Nn * Dd;

        // 1) x RMSNorm for this batch
        rmsnorm_kernel<<<Nn, 256, 0, stream>>>(xb, gamma, xn);

        // 2) logits = xn @ se^T  [4096 x 4096], K=1024
        sgemm_kernel<0, 1, 0><<<dim3(ES / BN, Nn / BM, 1), 256, 0, stream>>>(
            xn, se, logits, Dd, Dd, Dd, ES, nullptr, nullptr, 0, 0, 0, 0);

        // 3) softmax stats
        colstats_partial<<<dim3(16, 8), 256, 0, stream>>>(logits, pstats);
        colstats_combine<<<16, 256, 0, stream>>>(pstats, dstats);
        rowstats_kernel<<<Nn, 256, 0, stream>>>(logits, cstats);

        // 4) slots[es,d] = sum_n dispatch[n,es] * xn[n,d]
        sgemm_kernel<2, 0, 0><<<dim3(Dd / BN, ES / BM, 1), 256, 0, stream>>>(
            logits, xn, slots, Nn, ES, Dd, Dd, dstats, nullptr, 0, 0, 0, 0);

        // 5) per-expert FFN, z-batched over the 8 experts
        //    hid[e rows] = gelu(slots[e rows] @ w1_e + b1_e)
        sgemm_kernel<0, 0, 1><<<dim3(Hh / BN, Ss / BM, Ee), 256, 0, stream>>>(
            slots, w1, hid, Dd, Dd, Hh, Hh, nullptr, b1,
            (long long)Ss * Dd, (long long)Dd * Hh, (long long)Ss * Hh, Hh);
        //    outb[e rows] = hid[e rows] @ w2_e + b2_e
        sgemm_kernel<0, 0, 2><<<dim3(Dd / BN, Ss / BM, Ee), 256, 0, stream>>>(
            hid, w2, outb, Hh, Hh, Dd, Dd, nullptr, b2,
            (long long)Ss * Hh, (long long)Hh * Dd, (long long)Ss * Dd, Dd);

        // 6) y[n,d] = sum_es combine[n,es] * outb[es,d]
        sgemm_kernel<3, 0, 0><<<dim3(Dd / BN, Nn / BM, 1), 256, 0, stream>>>(
            logits, outb, out + (size_t)b * Nn * Dd,
            ES, ES, Dd, Dd, cstats, nullptr, 0, 0, 0, 0);
    }

    (void)in_sizes; (void)n_in; (void)out_size;
}